// Round 1
// baseline (1400.992 us; speedup 1.0000x reference)
//
#include <hip/hip_runtime.h>

#define NN 12288
#define NE 6144
#define ND 256

typedef __attribute__((ext_vector_type(8))) short short8;
typedef __attribute__((ext_vector_type(4))) float f32x4;
typedef unsigned short u16;
typedef unsigned int u32;

__device__ inline u16 f2bf(float f) {
  union { float f; u32 u; } v; v.f = f;
  u32 r = v.u + 0x7fffu + ((v.u >> 16) & 1u);
  return (u16)(r >> 16);
}

__device__ inline void gll16(const void* g, void* l) {
  __builtin_amdgcn_global_load_lds(
      (const __attribute__((address_space(1))) u32*)g,
      (__attribute__((address_space(3))) u32*)l, 16, 0, 0);
}

// Stage B tile [256 n][32 k] bf16 into LDS via global_load_lds (16B/lane),
// swizzled: global chunk c of row n lands at position (c + (n>>1)) & 3.
__device__ inline void stage_B(const u16* __restrict__ Bg, int ldb, int k0,
                               u16* __restrict__ Blds) {
  const int w = threadIdx.x >> 6;
  const int lane = threadIdx.x & 63;
  const int dd = lane >> 2, p = lane & 3;
#pragma unroll
  for (int s = 0; s < 4; ++s) {
    const int dbase = (w * 4 + s) * 16;
    const int n = dbase + dd;
    const int c = (p - (n >> 1)) & 3;
    gll16(Bg + (size_t)n * ldb + k0 + c * 8, Blds + dbase * 32);
  }
}

__device__ inline short8 load_B(const u16* __restrict__ Blds, int n, int quad) {
  const int p = (quad + (n >> 1)) & 3;
  return *(const short8*)(Blds + n * 32 + p * 8);
}

// ---------------- kernel 1: xn_t[d][v] = dv[v]*(x@W + b)  (bf16, transposed)
__global__ __launch_bounds__(256) void k_xform(
    const float* __restrict__ x, const u16* __restrict__ Wt,
    const float* __restrict__ b, const float* __restrict__ dv,
    u16* __restrict__ xnt) {
  __shared__ u16 Alds[64 * 40];
  __shared__ u16 Blds[256 * 32];
  const int tid = threadIdx.x;
  const int w = tid >> 6, lane = tid & 63, ln = lane & 15, quad = lane >> 4;
  const int m0 = blockIdx.x * 64;
  const int am = tid >> 2, ac = (tid & 3) * 8;
  f32x4 acc[4][4] = {};
  for (int kt = 0; kt < ND / 32; ++kt) {
    const int k0 = kt * 32;
    __syncthreads();
    stage_B(Wt, ND, k0, Blds);
    const float4* pa = (const float4*)(x + (size_t)(m0 + am) * ND + k0 + ac);
    float4 f0 = pa[0], f1 = pa[1];
    short8 av;
    av[0] = (short)f2bf(f0.x); av[1] = (short)f2bf(f0.y);
    av[2] = (short)f2bf(f0.z); av[3] = (short)f2bf(f0.w);
    av[4] = (short)f2bf(f1.x); av[5] = (short)f2bf(f1.y);
    av[6] = (short)f2bf(f1.z); av[7] = (short)f2bf(f1.w);
    *(short8*)(Alds + am * 40 + ac) = av;
    __syncthreads();
    short8 af[4];
#pragma unroll
    for (int mt = 0; mt < 4; ++mt)
      af[mt] = *(const short8*)(Alds + (mt * 16 + ln) * 40 + quad * 8);
#pragma unroll
    for (int nt = 0; nt < 4; ++nt) {
      short8 bf = load_B(Blds, w * 64 + nt * 16 + ln, quad);
#pragma unroll
      for (int mt = 0; mt < 4; ++mt)
        acc[nt][mt] = __builtin_amdgcn_mfma_f32_16x16x32_bf16(af[mt], bf, acc[nt][mt], 0, 0, 0);
    }
  }
#pragma unroll
  for (int nt = 0; nt < 4; ++nt) {
    const int d = w * 64 + nt * 16 + ln;
    const float bb = b[d];
#pragma unroll
    for (int mt = 0; mt < 4; ++mt) {
      const int vb = m0 + mt * 16 + quad * 4;
      f32x4 a = acc[nt][mt];
      union { u16 h[4]; uint2 u; } pk;
#pragma unroll
      for (int r = 0; r < 4; ++r) pk.h[r] = f2bf(dv[vb + r] * (a[r] + bb));
      *(uint2*)(xnt + (size_t)d * NN + vb) = pk.u;
    }
  }
}

// ---------------- GEMM1: xhe_t[d][e] = de[e] * (H^T @ xn)  (bf16, transposed)
__global__ __launch_bounds__(256) void k_gemm1(
    const float* __restrict__ H, const u16* __restrict__ xnt,
    const float* __restrict__ de, u16* __restrict__ xhet) {
  __shared__ u16 Alds[32 * 40];
  __shared__ u16 Blds[256 * 32];
  const int tid = threadIdx.x;
  const int w = tid >> 6, lane = tid & 63, ln = lane & 15, quad = lane >> 4;
  const int e0 = blockIdx.x * 32;
  const int ec = tid & 31, rp0 = tid >> 5;
  f32x4 acc[4][2] = {};
  for (int kt = 0; kt < NN / 32; ++kt) {
    const int k0 = kt * 32;
    __syncthreads();
    stage_B(xnt, NN, k0, Blds);
    // A = H^T tile: load H[v][e] pairs of v-rows, pack 2 bf16, write transposed
#pragma unroll
    for (int i = 0; i < 2; ++i) {
      const int rp = rp0 + i * 8;   // 0..15 row-pairs
      const int vl = rp * 2;
      float g0 = H[(size_t)(k0 + vl) * NE + e0 + ec];
      float g1 = H[(size_t)(k0 + vl + 1) * NE + e0 + ec];
      u32 pk = (u32)f2bf(g0) | ((u32)f2bf(g1) << 16);
      *(u32*)(Alds + ec * 40 + vl) = pk;
    }
    __syncthreads();
    short8 af[2];
#pragma unroll
    for (int mt = 0; mt < 2; ++mt)
      af[mt] = *(const short8*)(Alds + (mt * 16 + ln) * 40 + quad * 8);
#pragma unroll
    for (int nt = 0; nt < 4; ++nt) {
      short8 bf = load_B(Blds, w * 64 + nt * 16 + ln, quad);
#pragma unroll
      for (int mt = 0; mt < 2; ++mt)
        acc[nt][mt] = __builtin_amdgcn_mfma_f32_16x16x32_bf16(af[mt], bf, acc[nt][mt], 0, 0, 0);
    }
  }
#pragma unroll
  for (int nt = 0; nt < 4; ++nt) {
    const int d = w * 64 + nt * 16 + ln;
#pragma unroll
    for (int mt = 0; mt < 2; ++mt) {
      const int eb = e0 + mt * 16 + quad * 4;
      f32x4 a = acc[nt][mt];
      union { u16 h[4]; uint2 u; } pk;
#pragma unroll
      for (int r = 0; r < 4; ++r) pk.h[r] = f2bf(de[eb + r] * a[r]);
      *(uint2*)(xhet + (size_t)d * NE + eb) = pk.u;
    }
  }
}

// ---------------- GEMM2: out[v][d] = dv[v] * (H @ xhe_n)  (f32, natural)
__global__ __launch_bounds__(256) void k_gemm2(
    const float* __restrict__ H, const u16* __restrict__ xhet,
    const float* __restrict__ dv, float* __restrict__ out) {
  __shared__ u16 Alds[64 * 40];
  __shared__ u16 Blds[256 * 32];
  const int tid = threadIdx.x;
  const int w = tid >> 6, lane = tid & 63, ln = lane & 15, quad = lane >> 4;
  const int m0 = blockIdx.x * 64;
  const int am = tid >> 2, ac = (tid & 3) * 8;
  f32x4 acc[4][4] = {};
  for (int kt = 0; kt < NE / 32; ++kt) {
    const int k0 = kt * 32;
    __syncthreads();
    stage_B(xhet, NE, k0, Blds);
    const float4* pa = (const float4*)(H + (size_t)(m0 + am) * NE + k0 + ac);
    float4 f0 = pa[0], f1 = pa[1];
    short8 av;
    av[0] = (short)f2bf(f0.x); av[1] = (short)f2bf(f0.y);
    av[2] = (short)f2bf(f0.z); av[3] = (short)f2bf(f0.w);
    av[4] = (short)f2bf(f1.x); av[5] = (short)f2bf(f1.y);
    av[6] = (short)f2bf(f1.z); av[7] = (short)f2bf(f1.w);
    *(short8*)(Alds + am * 40 + ac) = av;
    __syncthreads();
    short8 af[4];
#pragma unroll
    for (int mt = 0; mt < 4; ++mt)
      af[mt] = *(const short8*)(Alds + (mt * 16 + ln) * 40 + quad * 8);
#pragma unroll
    for (int nt = 0; nt < 4; ++nt) {
      short8 bf = load_B(Blds, w * 64 + nt * 16 + ln, quad);
#pragma unroll
      for (int mt = 0; mt < 4; ++mt)
        acc[nt][mt] = __builtin_amdgcn_mfma_f32_16x16x32_bf16(af[mt], bf, acc[nt][mt], 0, 0, 0);
    }
  }
#pragma unroll
  for (int nt = 0; nt < 4; ++nt) {
    const int d = w * 64 + nt * 16 + ln;
#pragma unroll
    for (int mt = 0; mt < 4; ++mt) {
      const int vb = m0 + mt * 16 + quad * 4;
      f32x4 a = acc[nt][mt];
#pragma unroll
      for (int r = 0; r < 4; ++r)
        out[(size_t)(vb + r) * ND + d] = dv[vb + r] * a[r];
    }
  }
}

// ---------------- prep: diag extraction + W transpose to bf16
__global__ __launch_bounds__(256) void k_prep(
    const float* __restrict__ W, const float* __restrict__ Dv,
    const float* __restrict__ De, u16* __restrict__ Wt,
    float* __restrict__ dv, float* __restrict__ de) {
  const int t = blockIdx.x * 256 + threadIdx.x;   // 65536 threads
  const int d = t >> 8, k = t & 255;
  Wt[d * 256 + k] = f2bf(W[k * 256 + d]);
  if (t < NN) dv[t] = Dv[(size_t)t * (NN + 1)];
  if (t < NE) de[t] = De[(size_t)t * (NE + 1)];
}

extern "C" void kernel_launch(void* const* d_in, const int* in_sizes, int n_in,
                              void* d_out, int out_size, void* d_ws, size_t ws_size,
                              hipStream_t stream) {
  const float* x  = (const float*)d_in[0];
  const float* H  = (const float*)d_in[1];
  const float* Dv = (const float*)d_in[2];
  const float* De = (const float*)d_in[3];
  const float* W  = (const float*)d_in[4];
  const float* b  = (const float*)d_in[5];
  float* out = (float*)d_out;
  char* ws = (char*)d_ws;
  u16* xnt  = (u16*)ws;                      // 256 x 12288 bf16 = 6291456 B
  u16* xhet = (u16*)(ws + 6291456);          // 256 x 6144 bf16  = 3145728 B
  u16* Wt   = (u16*)(ws + 9437184);          // 256 x 256 bf16   = 131072 B
  float* dv = (float*)(ws + 9568256);        // 12288 f32
  float* de = (float*)(ws + 9617408);        // 6144 f32

  hipLaunchKernelGGL(k_prep,  dim3(256), dim3(256), 0, stream, W, Dv, De, Wt, dv, de);
  hipLaunchKernelGGL(k_xform, dim3(NN / 64), dim3(256), 0, stream, x, Wt, b, dv, xnt);
  hipLaunchKernelGGL(k_gemm1, dim3(NE / 32), dim3(256), 0, stream, H, xnt, de, xhet);
  hipLaunchKernelGGL(k_gemm2, dim3(NN / 64), dim3(256), 0, stream, H, xhet, dv, out);
}

// Round 2
// 1130.554 us; speedup vs baseline: 1.2392x; 1.2392x over previous
//
#include <hip/hip_runtime.h>

#define NN 12288
#define NE 6144
#define ND 256

typedef __attribute__((ext_vector_type(8))) short short8;
typedef __attribute__((ext_vector_type(4))) float f32x4;
typedef unsigned short u16;
typedef unsigned int u32;

__device__ inline u16 f2bf(float f) {
  union { float f; u32 u; } v; v.f = f;
  u32 r = v.u + 0x7fffu + ((v.u >> 16) & 1u);
  return (u16)(r >> 16);
}

__device__ inline void gll16(const void* g, void* l) {
  __builtin_amdgcn_global_load_lds(
      (const __attribute__((address_space(1))) u32*)g,
      (__attribute__((address_space(3))) u32*)l, 16, 0, 0);
}

// Stage B tile [256 n][32 k] bf16 into LDS via global_load_lds (16B/lane),
// swizzled: global chunk c of row n lands at position (c + (n>>1)) & 3.
__device__ inline void stage_B(const u16* __restrict__ Bg, int ldb, int k0,
                               u16* __restrict__ Blds) {
  const int w = threadIdx.x >> 6;
  const int lane = threadIdx.x & 63;
  const int dd = lane >> 2, p = lane & 3;
#pragma unroll
  for (int s = 0; s < 4; ++s) {
    const int dbase = (w * 4 + s) * 16;
    const int n = dbase + dd;
    const int c = (p - (n >> 1)) & 3;
    gll16(Bg + (size_t)n * ldb + k0 + c * 8, Blds + dbase * 32);
  }
}

__device__ inline short8 load_B(const u16* __restrict__ Blds, int n, int quad) {
  const int p = (quad + (n >> 1)) & 3;
  return *(const short8*)(Blds + n * 32 + p * 8);
}

// ---------------- kernel 1: xn_t[d][v] = dv[v]*(x@W + b)  (bf16, transposed)
__global__ __launch_bounds__(256) void k_xform(
    const float* __restrict__ x, const u16* __restrict__ Wt,
    const float* __restrict__ b, const float* __restrict__ dv,
    u16* __restrict__ xnt) {
  __shared__ u16 Alds[64 * 40];
  __shared__ u16 Blds[256 * 32];
  const int tid = threadIdx.x;
  const int w = tid >> 6, lane = tid & 63, ln = lane & 15, quad = lane >> 4;
  const int m0 = blockIdx.x * 64;
  const int am = tid >> 2, ac = (tid & 3) * 8;
  f32x4 acc[4][4] = {};
  for (int kt = 0; kt < ND / 32; ++kt) {
    const int k0 = kt * 32;
    __syncthreads();
    stage_B(Wt, ND, k0, Blds);
    const float4* pa = (const float4*)(x + (size_t)(m0 + am) * ND + k0 + ac);
    float4 f0 = pa[0], f1 = pa[1];
    short8 av;
    av[0] = (short)f2bf(f0.x); av[1] = (short)f2bf(f0.y);
    av[2] = (short)f2bf(f0.z); av[3] = (short)f2bf(f0.w);
    av[4] = (short)f2bf(f1.x); av[5] = (short)f2bf(f1.y);
    av[6] = (short)f2bf(f1.z); av[7] = (short)f2bf(f1.w);
    *(short8*)(Alds + am * 40 + ac) = av;
    __syncthreads();
    short8 af[4];
#pragma unroll
    for (int mt = 0; mt < 4; ++mt)
      af[mt] = *(const short8*)(Alds + (mt * 16 + ln) * 40 + quad * 8);
#pragma unroll
    for (int nt = 0; nt < 4; ++nt) {
      short8 bf = load_B(Blds, w * 64 + nt * 16 + ln, quad);
#pragma unroll
      for (int mt = 0; mt < 4; ++mt)
        acc[nt][mt] = __builtin_amdgcn_mfma_f32_16x16x32_bf16(af[mt], bf, acc[nt][mt], 0, 0, 0);
    }
  }
#pragma unroll
  for (int nt = 0; nt < 4; ++nt) {
    const int d = w * 64 + nt * 16 + ln;
    const float bb = b[d];
#pragma unroll
    for (int mt = 0; mt < 4; ++mt) {
      const int vb = m0 + mt * 16 + quad * 4;
      f32x4 a = acc[nt][mt];
      union { u16 h[4]; uint2 u; } pk;
#pragma unroll
      for (int r = 0; r < 4; ++r) pk.h[r] = f2bf(dv[vb + r] * (a[r] + bb));
      *(uint2*)(xnt + (size_t)d * NN + vb) = pk.u;
    }
  }
}

// ---------------- GEMM1 split-K: acc1[e][d] += (H^T @ xn) chunk  (f32 atomics)
// grid (96, 8): blockIdx.x = e-tile (64 e), blockIdx.y = k-chunk (1536 v)
__global__ __launch_bounds__(256) void k_gemm1s(
    const float* __restrict__ H, const u16* __restrict__ xnt,
    float* __restrict__ acc1) {
  __shared__ u16 Alds[64 * 40];
  __shared__ u16 Blds[256 * 32];
  const int tid = threadIdx.x;
  const int w = tid >> 6, lane = tid & 63, ln = lane & 15, quad = lane >> 4;
  const int e0 = blockIdx.x * 64;
  const int kbase = blockIdx.y * 1536;
  // A-staging thread mapping: p2 = dword-slot group, ea = e within tile
  const int p2 = tid & 3, ea = tid >> 2;
  f32x4 acc[4][4] = {};
  for (int kt = 0; kt < 48; ++kt) {
    const int k0 = kbase + kt * 32;
    __syncthreads();
    stage_B(xnt, NN, k0, Blds);
    // A = H^T tile [64 e][32 v]: pack v-pairs into dwords, transposed in LDS.
#pragma unroll
    for (int i = 0; i < 4; ++i) {
      const int p = p2 + i * 4;              // v-pair index 0..15
      const int v = k0 + p * 2;
      float g0 = H[(size_t)v * NE + e0 + ea];
      float g1 = H[(size_t)(v + 1) * NE + e0 + ea];
      u32 pk = (u32)f2bf(g0) | ((u32)f2bf(g1) << 16);
      *(u32*)(Alds + ea * 40 + p * 2) = pk;
    }
    __syncthreads();
    short8 af[4];
#pragma unroll
    for (int mt = 0; mt < 4; ++mt)
      af[mt] = *(const short8*)(Alds + (mt * 16 + ln) * 40 + quad * 8);
#pragma unroll
    for (int nt = 0; nt < 4; ++nt) {
      short8 bf = load_B(Blds, w * 64 + nt * 16 + ln, quad);
#pragma unroll
      for (int mt = 0; mt < 4; ++mt)
        acc[nt][mt] = __builtin_amdgcn_mfma_f32_16x16x32_bf16(af[mt], bf, acc[nt][mt], 0, 0, 0);
    }
  }
#pragma unroll
  for (int nt = 0; nt < 4; ++nt) {
    const int d = w * 64 + nt * 16 + ln;
#pragma unroll
    for (int mt = 0; mt < 4; ++mt) {
      const int eb = e0 + mt * 16 + quad * 4;
      f32x4 a = acc[nt][mt];
#pragma unroll
      for (int r = 0; r < 4; ++r)
        atomicAdd(acc1 + (size_t)(eb + r) * ND + d, a[r]);
    }
  }
}

// ---------------- scale1: xhet[d][e] = bf16(de[e] * acc1[e][d])
// grid NE/16: block covers 16 e x 256 d; thread = d.
__global__ __launch_bounds__(256) void k_scale1(
    const float* __restrict__ acc1, const float* __restrict__ de,
    u16* __restrict__ xhet) {
  const int tid = threadIdx.x;
  const int e0 = blockIdx.x * 16;
  union { u16 h[16]; uint4 q[2]; } pk;
#pragma unroll
  for (int i = 0; i < 16; ++i)
    pk.h[i] = f2bf(de[e0 + i] * acc1[(size_t)(e0 + i) * ND + tid]);
  uint4* dst = (uint4*)(xhet + (size_t)tid * NE + e0);
  dst[0] = pk.q[0];
  dst[1] = pk.q[1];
}

// ---------------- GEMM2 split-K: out[v][d] += dv[v] * (H @ xhe_n) chunk
// grid (192, 4): blockIdx.x = v-tile (64 v), blockIdx.y = k-chunk (1536 e)
__global__ __launch_bounds__(256) void k_gemm2s(
    const float* __restrict__ H, const u16* __restrict__ xhet,
    const float* __restrict__ dv, float* __restrict__ out) {
  __shared__ u16 Alds[64 * 40];
  __shared__ u16 Blds[256 * 32];
  const int tid = threadIdx.x;
  const int w = tid >> 6, lane = tid & 63, ln = lane & 15, quad = lane >> 4;
  const int m0 = blockIdx.x * 64;
  const int kbase = blockIdx.y * 1536;
  const int am = tid >> 2, ac = (tid & 3) * 8;
  f32x4 acc[4][4] = {};
  for (int kt = 0; kt < 48; ++kt) {
    const int k0 = kbase + kt * 32;
    __syncthreads();
    stage_B(xhet, NE, k0, Blds);
    const float4* pa = (const float4*)(H + (size_t)(m0 + am) * NE + k0 + ac);
    float4 f0 = pa[0], f1 = pa[1];
    short8 av;
    av[0] = (short)f2bf(f0.x); av[1] = (short)f2bf(f0.y);
    av[2] = (short)f2bf(f0.z); av[3] = (short)f2bf(f0.w);
    av[4] = (short)f2bf(f1.x); av[5] = (short)f2bf(f1.y);
    av[6] = (short)f2bf(f1.z); av[7] = (short)f2bf(f1.w);
    *(short8*)(Alds + am * 40 + ac) = av;
    __syncthreads();
    short8 af[4];
#pragma unroll
    for (int mt = 0; mt < 4; ++mt)
      af[mt] = *(const short8*)(Alds + (mt * 16 + ln) * 40 + quad * 8);
#pragma unroll
    for (int nt = 0; nt < 4; ++nt) {
      short8 bf = load_B(Blds, w * 64 + nt * 16 + ln, quad);
#pragma unroll
      for (int mt = 0; mt < 4; ++mt)
        acc[nt][mt] = __builtin_amdgcn_mfma_f32_16x16x32_bf16(af[mt], bf, acc[nt][mt], 0, 0, 0);
    }
  }
#pragma unroll
  for (int nt = 0; nt < 4; ++nt) {
    const int d = w * 64 + nt * 16 + ln;
#pragma unroll
    for (int mt = 0; mt < 4; ++mt) {
      const int vb = m0 + mt * 16 + quad * 4;
      f32x4 a = acc[nt][mt];
#pragma unroll
      for (int r = 0; r < 4; ++r)
        atomicAdd(out + (size_t)(vb + r) * ND + d, dv[vb + r] * a[r]);
    }
  }
}

// ---------------- prep: diag extraction + W transpose to bf16
__global__ __launch_bounds__(256) void k_prep(
    const float* __restrict__ W, const float* __restrict__ Dv,
    const float* __restrict__ De, u16* __restrict__ Wt,
    float* __restrict__ dv, float* __restrict__ de) {
  const int t = blockIdx.x * 256 + threadIdx.x;   // 65536 threads
  const int d = t >> 8, k = t & 255;
  Wt[d * 256 + k] = f2bf(W[k * 256 + d]);
  if (t < NN) dv[t] = Dv[(size_t)t * (NN + 1)];
  if (t < NE) de[t] = De[(size_t)t * (NE + 1)];
}

extern "C" void kernel_launch(void* const* d_in, const int* in_sizes, int n_in,
                              void* d_out, int out_size, void* d_ws, size_t ws_size,
                              hipStream_t stream) {
  const float* x  = (const float*)d_in[0];
  const float* H  = (const float*)d_in[1];
  const float* Dv = (const float*)d_in[2];
  const float* De = (const float*)d_in[3];
  const float* W  = (const float*)d_in[4];
  const float* b  = (const float*)d_in[5];
  float* out = (float*)d_out;
  char* ws = (char*)d_ws;
  u16* xnt   = (u16*)ws;                      // 256 x 12288 bf16 = 6291456 B
  u16* xhet  = (u16*)(ws + 6291456);          // 256 x 6144 bf16  = 3145728 B
  u16* Wt    = (u16*)(ws + 9437184);          // 256 x 256 bf16   = 131072 B
  float* dv  = (float*)(ws + 9568256);        // 12288 f32
  float* de  = (float*)(ws + 9617408);        // 6144 f32
  float* acc1 = (float*)(ws + 9641984);       // 6144 x 256 f32 = 6291456 B

  hipMemsetAsync(acc1, 0, (size_t)NE * ND * sizeof(float), stream);
  hipMemsetAsync(out, 0, (size_t)NN * ND * sizeof(float), stream);
  hipLaunchKernelGGL(k_prep,   dim3(256), dim3(256), 0, stream, W, Dv, De, Wt, dv, de);
  hipLaunchKernelGGL(k_xform,  dim3(NN / 64), dim3(256), 0, stream, x, Wt, b, dv, xnt);
  hipLaunchKernelGGL(k_gemm1s, dim3(NE / 64, 8), dim3(256), 0, stream, H, xnt, acc1);
  hipLaunchKernelGGL(k_scale1, dim3(NE / 16), dim3(256), 0, stream, acc1, de, xhet);
  hipLaunchKernelGGL(k_gemm2s, dim3(NN / 64, 4), dim3(256), 0, stream, H, xhet, dv, out);
}

// Round 3
// 1079.809 us; speedup vs baseline: 1.2974x; 1.0470x over previous
//
#include <hip/hip_runtime.h>

#define NN 12288
#define NE 6144
#define ND 256

typedef __attribute__((ext_vector_type(8))) short short8;
typedef __attribute__((ext_vector_type(4))) float f32x4;
typedef unsigned short u16;
typedef unsigned int u32;

__device__ inline u16 f2bf(float f) {
  union { float f; u32 u; } v; v.f = f;
  u32 r = v.u + 0x7fffu + ((v.u >> 16) & 1u);
  return (u16)(r >> 16);
}

__device__ inline void gll16(const void* g, void* l) {
  __builtin_amdgcn_global_load_lds(
      (const __attribute__((address_space(1))) u32*)g,
      (__attribute__((address_space(3))) u32*)l, 16, 0, 0);
}

// Stage B tile [256 n][32 k] bf16 into LDS via global_load_lds (16B/lane),
// swizzled: global chunk c of row n lands at position (c + (n>>1)) & 3.
__device__ inline void stage_B(const u16* __restrict__ Bg, int ldb, int k0,
                               u16* __restrict__ Blds) {
  const int w = threadIdx.x >> 6;
  const int lane = threadIdx.x & 63;
  const int dd = lane >> 2, p = lane & 3;
#pragma unroll
  for (int s = 0; s < 4; ++s) {
    const int dbase = (w * 4 + s) * 16;
    const int n = dbase + dd;
    const int c = (p - (n >> 1)) & 3;
    gll16(Bg + (size_t)n * ldb + k0 + c * 8, Blds + dbase * 32);
  }
}

__device__ inline short8 load_B(const u16* __restrict__ Blds, int n, int quad) {
  const int p = (quad + (n >> 1)) & 3;
  return *(const short8*)(Blds + n * 32 + p * 8);
}

// ---------------- kernel 1: xn_t[d][v] = dv[v]*(x@W + b)  (bf16, transposed)
__global__ __launch_bounds__(256) void k_xform(
    const float* __restrict__ x, const u16* __restrict__ Wt,
    const float* __restrict__ b, const float* __restrict__ dv,
    u16* __restrict__ xnt) {
  __shared__ u16 Alds[64 * 40];
  __shared__ u16 Blds[256 * 32];
  const int tid = threadIdx.x;
  const int w = tid >> 6, lane = tid & 63, ln = lane & 15, quad = lane >> 4;
  const int m0 = blockIdx.x * 64;
  const int am = tid >> 2, ac = (tid & 3) * 8;
  f32x4 acc[4][4] = {};
  for (int kt = 0; kt < ND / 32; ++kt) {
    const int k0 = kt * 32;
    __syncthreads();
    stage_B(Wt, ND, k0, Blds);
    const float4* pa = (const float4*)(x + (size_t)(m0 + am) * ND + k0 + ac);
    float4 f0 = pa[0], f1 = pa[1];
    short8 av;
    av[0] = (short)f2bf(f0.x); av[1] = (short)f2bf(f0.y);
    av[2] = (short)f2bf(f0.z); av[3] = (short)f2bf(f0.w);
    av[4] = (short)f2bf(f1.x); av[5] = (short)f2bf(f1.y);
    av[6] = (short)f2bf(f1.z); av[7] = (short)f2bf(f1.w);
    *(short8*)(Alds + am * 40 + ac) = av;
    __syncthreads();
    short8 af[4];
#pragma unroll
    for (int mt = 0; mt < 4; ++mt)
      af[mt] = *(const short8*)(Alds + (mt * 16 + ln) * 40 + quad * 8);
#pragma unroll
    for (int nt = 0; nt < 4; ++nt) {
      short8 bf = load_B(Blds, w * 64 + nt * 16 + ln, quad);
#pragma unroll
      for (int mt = 0; mt < 4; ++mt)
        acc[nt][mt] = __builtin_amdgcn_mfma_f32_16x16x32_bf16(af[mt], bf, acc[nt][mt], 0, 0, 0);
    }
  }
#pragma unroll
  for (int nt = 0; nt < 4; ++nt) {
    const int d = w * 64 + nt * 16 + ln;
    const float bb = b[d];
#pragma unroll
    for (int mt = 0; mt < 4; ++mt) {
      const int vb = m0 + mt * 16 + quad * 4;
      f32x4 a = acc[nt][mt];
      union { u16 h[4]; uint2 u; } pk;
#pragma unroll
      for (int r = 0; r < 4; ++r) pk.h[r] = f2bf(dv[vb + r] * (a[r] + bb));
      *(uint2*)(xnt + (size_t)d * NN + vb) = pk.u;
    }
  }
}

// ---------------- GEMM1 split-K: P1[chunk][e][d] = (H^T @ xn) chunk partial
// grid (96, 8): blockIdx.x = e-tile (64 e), blockIdx.y = k-chunk (1536 v)
__global__ __launch_bounds__(256) void k_gemm1s(
    const float* __restrict__ H, const u16* __restrict__ xnt,
    float* __restrict__ P1) {
  __shared__ u16 Alds[64 * 40];
  __shared__ u16 Blds[256 * 32];
  const int tid = threadIdx.x;
  const int w = tid >> 6, lane = tid & 63, ln = lane & 15, quad = lane >> 4;
  const int e0 = blockIdx.x * 64;
  const int kbase = blockIdx.y * 1536;
  const int p2 = tid & 3, ea = tid >> 2;
  f32x4 acc[4][4] = {};
  for (int kt = 0; kt < 48; ++kt) {
    const int k0 = kbase + kt * 32;
    __syncthreads();
    stage_B(xnt, NN, k0, Blds);
    // A = H^T tile [64 e][32 v]: pack v-pairs into dwords, transposed in LDS.
#pragma unroll
    for (int i = 0; i < 4; ++i) {
      const int p = p2 + i * 4;              // v-pair index 0..15
      const int v = k0 + p * 2;
      float g0 = H[(size_t)v * NE + e0 + ea];
      float g1 = H[(size_t)(v + 1) * NE + e0 + ea];
      u32 pk = (u32)f2bf(g0) | ((u32)f2bf(g1) << 16);
      *(u32*)(Alds + ea * 40 + p * 2) = pk;
    }
    __syncthreads();
    short8 af[4];
#pragma unroll
    for (int mt = 0; mt < 4; ++mt)
      af[mt] = *(const short8*)(Alds + (mt * 16 + ln) * 40 + quad * 8);
#pragma unroll
    for (int nt = 0; nt < 4; ++nt) {
      short8 bf = load_B(Blds, w * 64 + nt * 16 + ln, quad);
#pragma unroll
      for (int mt = 0; mt < 4; ++mt)
        acc[nt][mt] = __builtin_amdgcn_mfma_f32_16x16x32_bf16(af[mt], bf, acc[nt][mt], 0, 0, 0);
    }
  }
  float* P = P1 + (size_t)blockIdx.y * NE * ND;
#pragma unroll
  for (int nt = 0; nt < 4; ++nt) {
    const int d = w * 64 + nt * 16 + ln;
#pragma unroll
    for (int mt = 0; mt < 4; ++mt) {
      const int eb = e0 + mt * 16 + quad * 4;
      f32x4 a = acc[nt][mt];
#pragma unroll
      for (int r = 0; r < 4; ++r)
        P[(size_t)(eb + r) * ND + d] = a[r];
    }
  }
}

// ---------------- red1: xhet[d][e] = bf16(de[e] * sum_c P1[c][e][d])
// grid NE/16: block covers 16 e x 256 d; thread = d.
__global__ __launch_bounds__(256) void k_red1(
    const float* __restrict__ P1, const float* __restrict__ de,
    u16* __restrict__ xhet) {
  const int tid = threadIdx.x;
  const int e0 = blockIdx.x * 16;
  union { u16 h[16]; uint4 q[2]; } pk;
#pragma unroll
  for (int i = 0; i < 16; ++i) {
    float s = 0.f;
#pragma unroll
    for (int c = 0; c < 8; ++c)
      s += P1[(size_t)c * NE * ND + (size_t)(e0 + i) * ND + tid];
    pk.h[i] = f2bf(de[e0 + i] * s);
  }
  uint4* dst = (uint4*)(xhet + (size_t)tid * NE + e0);
  dst[0] = pk.q[0];
  dst[1] = pk.q[1];
}

// ---------------- GEMM2 split-K: P2[chunk][v][d] = (H @ xhe_n) chunk partial
// grid (192, 4): blockIdx.x = v-tile (64 v), blockIdx.y = k-chunk (1536 e)
__global__ __launch_bounds__(256) void k_gemm2s(
    const float* __restrict__ H, const u16* __restrict__ xhet,
    float* __restrict__ P2) {
  __shared__ u16 Alds[64 * 40];
  __shared__ u16 Blds[256 * 32];
  const int tid = threadIdx.x;
  const int w = tid >> 6, lane = tid & 63, ln = lane & 15, quad = lane >> 4;
  const int m0 = blockIdx.x * 64;
  const int kbase = blockIdx.y * 1536;
  const int am = tid >> 2, ac = (tid & 3) * 8;
  f32x4 acc[4][4] = {};
  for (int kt = 0; kt < 48; ++kt) {
    const int k0 = kbase + kt * 32;
    __syncthreads();
    stage_B(xhet, NE, k0, Blds);
    const float4* pa = (const float4*)(H + (size_t)(m0 + am) * NE + k0 + ac);
    float4 f0 = pa[0], f1 = pa[1];
    short8 av;
    av[0] = (short)f2bf(f0.x); av[1] = (short)f2bf(f0.y);
    av[2] = (short)f2bf(f0.z); av[3] = (short)f2bf(f0.w);
    av[4] = (short)f2bf(f1.x); av[5] = (short)f2bf(f1.y);
    av[6] = (short)f2bf(f1.z); av[7] = (short)f2bf(f1.w);
    *(short8*)(Alds + am * 40 + ac) = av;
    __syncthreads();
    short8 af[4];
#pragma unroll
    for (int mt = 0; mt < 4; ++mt)
      af[mt] = *(const short8*)(Alds + (mt * 16 + ln) * 40 + quad * 8);
#pragma unroll
    for (int nt = 0; nt < 4; ++nt) {
      short8 bf = load_B(Blds, w * 64 + nt * 16 + ln, quad);
#pragma unroll
      for (int mt = 0; mt < 4; ++mt)
        acc[nt][mt] = __builtin_amdgcn_mfma_f32_16x16x32_bf16(af[mt], bf, acc[nt][mt], 0, 0, 0);
    }
  }
  float* P = P2 + (size_t)blockIdx.y * NN * ND;
#pragma unroll
  for (int nt = 0; nt < 4; ++nt) {
    const int d = w * 64 + nt * 16 + ln;
#pragma unroll
    for (int mt = 0; mt < 4; ++mt) {
      const int vb = m0 + mt * 16 + quad * 4;
      f32x4 a = acc[nt][mt];
#pragma unroll
      for (int r = 0; r < 4; ++r)
        P[(size_t)(vb + r) * ND + d] = a[r];
    }
  }
}

// ---------------- red2: out[v][d] = dv[v] * sum_c P2[c][v][d]
// grid NN/16: block covers 16 v x 256 d; thread = d. Fully coalesced.
__global__ __launch_bounds__(256) void k_red2(
    const float* __restrict__ P2, const float* __restrict__ dv,
    float* __restrict__ out) {
  const int tid = threadIdx.x;
  const int v0 = blockIdx.x * 16;
#pragma unroll
  for (int i = 0; i < 16; ++i) {
    float s = 0.f;
#pragma unroll
    for (int c = 0; c < 4; ++c)
      s += P2[(size_t)c * NN * ND + (size_t)(v0 + i) * ND + tid];
    out[(size_t)(v0 + i) * ND + tid] = dv[v0 + i] * s;
  }
}

// ---------------- prep: diag extraction + W transpose to bf16
__global__ __launch_bounds__(256) void k_prep(
    const float* __restrict__ W, const float* __restrict__ Dv,
    const float* __restrict__ De, u16* __restrict__ Wt,
    float* __restrict__ dv, float* __restrict__ de) {
  const int t = blockIdx.x * 256 + threadIdx.x;   // 65536 threads
  const int d = t >> 8, k = t & 255;
  Wt[d * 256 + k] = f2bf(W[k * 256 + d]);
  if (t < NN) dv[t] = Dv[(size_t)t * (NN + 1)];
  if (t < NE) de[t] = De[(size_t)t * (NE + 1)];
}

extern "C" void kernel_launch(void* const* d_in, const int* in_sizes, int n_in,
                              void* d_out, int out_size, void* d_ws, size_t ws_size,
                              hipStream_t stream) {
  const float* x  = (const float*)d_in[0];
  const float* H  = (const float*)d_in[1];
  const float* Dv = (const float*)d_in[2];
  const float* De = (const float*)d_in[3];
  const float* W  = (const float*)d_in[4];
  const float* b  = (const float*)d_in[5];
  float* out = (float*)d_out;
  char* ws = (char*)d_ws;
  u16* xnt   = (u16*)ws;                      // 256 x 12288 bf16 = 6291456 B
  u16* xhet  = (u16*)(ws + 6291456);          // 256 x 6144 bf16  = 3145728 B
  u16* Wt    = (u16*)(ws + 9437184);          // 256 x 256 bf16   = 131072 B
  float* dv  = (float*)(ws + 9568256);        // 12288 f32
  float* de  = (float*)(ws + 9617408);        // 6144 f32
  float* P1  = (float*)(ws + 9641984);        // 8 x 6144 x 256 f32 = 50331648 B
  float* P2  = (float*)(ws + 59973632);       // 4 x 12288 x 256 f32 = 50331648 B

  hipLaunchKernelGGL(k_prep,   dim3(256), dim3(256), 0, stream, W, Dv, De, Wt, dv, de);
  hipLaunchKernelGGL(k_xform,  dim3(NN / 64), dim3(256), 0, stream, x, Wt, b, dv, xnt);
  hipLaunchKernelGGL(k_gemm1s, dim3(NE / 64, 8), dim3(256), 0, stream, H, xnt, P1);
  hipLaunchKernelGGL(k_red1,   dim3(NE / 16), dim3(256), 0, stream, P1, de, xhet);
  hipLaunchKernelGGL(k_gemm2s, dim3(NN / 64, 4), dim3(256), 0, stream, H, xhet, P2);
  hipLaunchKernelGGL(k_red2,   dim3(NN / 16), dim3(256), 0, stream, P2, dv, out);
}